// Round 11
// baseline (258.363 us; speedup 1.0000x reference)
//
#include <hip/hip_runtime.h>
#include <math.h>

#define NB    1024
#define NC    62
#define NBAND 5
#define NOUT  16
#define NHID  10
#define CW    33   // comHS row stride in u32 (odd -> conflict-free b32 access)

typedef __attribute__((ext_vector_type(2))) float f32x2;
typedef __attribute__((ext_vector_type(2))) _Float16 f16x2;
typedef __attribute__((ext_vector_type(2))) __fp16 fp16v2;   // cvt_pkrtz result type
#define FMA2(a, b, c) __builtin_elementwise_fma((a), (b), (c))
#define DOT2(a, b, c) __builtin_amdgcn_fdot2((a), (b), (c), false)

__device__ __forceinline__ f16x2 u2h(unsigned int u) { return __builtin_bit_cast(f16x2, u); }
__device__ __forceinline__ unsigned int pk2u(float x, float y) {
  const fp16v2 v = __builtin_amdgcn_cvt_pkrtz(x, y);
  return __builtin_bit_cast(unsigned int, v);
}

// =====================================================================
// Kernel A: gate-cancelled SPD (unchanged from round 10).
//   com[b,k] = 0.5*(N(relu(pcc_t)) + N(relu(A))) + 1e-5*I, f16 output.
// =====================================================================
__global__ __launch_bounds__(256) void k_spd(
    const float* __restrict__ pcc, const float* __restrict__ Aadj,
    const float* __restrict__ hlin_w, const float* __restrict__ elin_w,
    const float* __restrict__ att_w1,
    _Float16* __restrict__ comH, unsigned int* __restrict__ lwTHg,
    unsigned int* __restrict__ w1Hg, float* __restrict__ rsumG) {
  const int bk = (blockIdx.x & 7) * 640 + (blockIdx.x >> 3);  // XCD swizzle, 5120%8==0
  const int b = bk / NBAND, k = bk % NBAND;
  __shared__ __align__(16) unsigned int XcIH[31 * 64];   // 7936 B, f16x2 [ip][c]
  __shared__ float red4[4];
  const int tid = threadIdx.x;
  const int wave = tid >> 6, lane = tid & 63;
  const int p = tid >> 3, q8 = tid & 7, c0 = q8 * 8;
  const bool act = (p < 31);
  const int r0 = 2 * p, r1 = r0 + 1;

  float ld0[8], ld1[8];

  auto center_pack = [&](float (&a0)[8], float (&a1)[8]) -> void {
    float s0 = 0.f, s1 = 0.f;
#pragma unroll
    for (int u = 0; u < 8; ++u) { s0 += a0[u]; s1 += a1[u]; }
    s0 += __shfl_xor(s0, 1, 64); s0 += __shfl_xor(s0, 2, 64); s0 += __shfl_xor(s0, 4, 64);
    s1 += __shfl_xor(s1, 1, 64); s1 += __shfl_xor(s1, 2, 64); s1 += __shfl_xor(s1, 4, 64);
    const float m0 = s0 * (1.f / NC), m1 = s1 * (1.f / NC);
    float sq = 0.f;
    if (act) {
      unsigned int pk[8];
#pragma unroll
      for (int u = 0; u < 8; ++u) {
        const int c = c0 + u;
        const float cv0 = (c < NC) ? (a0[u] - m0) : 0.f;
        const float cv1 = (c < NC) ? (a1[u] - m1) : 0.f;
        sq += cv0 * cv0 + cv1 * cv1;
        pk[u] = pk2u(cv0, cv1);
      }
      uint4* d = reinterpret_cast<uint4*>(XcIH + p * 64 + c0);
      d[0] = make_uint4(pk[0], pk[1], pk[2], pk[3]);
      d[1] = make_uint4(pk[4], pk[5], pk[6], pk[7]);
    }
#pragma unroll
    for (int off = 1; off < 64; off <<= 1) sq += __shfl_xor(sq, off, 64);
    if (lane == 0) red4[wave] = sq;
  };

  // ---- src0 = relu(pcc[b,:,:,k]) : stride-5 scalar loads
#pragma unroll
  for (int u = 0; u < 8; ++u) { ld0[u] = 0.f; ld1[u] = 0.f; }
  if (act) {
    const float* s0p = pcc + ((size_t)(b * NC + r0) * NC + c0) * NBAND + k;
    const float* s1p = pcc + ((size_t)(b * NC + r1) * NC + c0) * NBAND + k;
#pragma unroll
    for (int u = 0; u < 8; ++u) {
      if (c0 + u < NC) {
        ld0[u] = fmaxf(s0p[u * NBAND], 0.f);
        ld1[u] = fmaxf(s1p[u * NBAND], 0.f);
      }
    }
  }
  center_pack(ld0, ld1);

  // prefetch src1 = Aadj rows
#pragma unroll
  for (int u = 0; u < 8; ++u) { ld0[u] = 0.f; ld1[u] = 0.f; }
  if (act) {
    const float* a0p = Aadj + ((size_t)(b * NBAND + k) * NC + r0) * NC + c0;
    const float* a1p = Aadj + ((size_t)(b * NBAND + k) * NC + r1) * NC + c0;
#pragma unroll
    for (int e = 0; e < 4; ++e) {
      const int c = c0 + 2 * e;
      if (c + 1 < NC) {
        const float2 v0 = *reinterpret_cast<const float2*>(a0p + 2 * e);
        const float2 v1 = *reinterpret_cast<const float2*>(a1p + 2 * e);
        ld0[2 * e] = v0.x; ld0[2 * e + 1] = v0.y;
        ld1[2 * e] = v1.x; ld1[2 * e + 1] = v1.y;
      } else if (c < NC) {
        ld0[2 * e] = a0p[2 * e];
        ld1[2 * e] = a1p[2 * e];
      }
    }
  }
  __syncthreads();   // (1) XcIH(src0) + red4 ready

  // ---- SYRK0: thread (tj,tl) owns G[4tj..][4tl..]; fdot2 over i-pairs
  const int tj = tid >> 4, tl = tid & 15;
  float acc0[16], acc1[16];
#pragma unroll
  for (int u = 0; u < 16; ++u) acc0[u] = 0.f;
  for (int ip = 0; ip < 31; ++ip) {
    const uint4 ju = *reinterpret_cast<const uint4*>(XcIH + ip * 64 + 4 * tj);
    const uint4 lu = *reinterpret_cast<const uint4*>(XcIH + ip * 64 + 4 * tl);
    const unsigned int jw[4] = {ju.x, ju.y, ju.z, ju.w};
    const unsigned int lw_[4] = {lu.x, lu.y, lu.z, lu.w};
#pragma unroll
    for (int jj = 0; jj < 4; ++jj)
#pragma unroll
      for (int e = 0; e < 4; ++e)
        acc0[jj * 4 + e] = DOT2(u2h(jw[jj]), u2h(lw_[e]), acc0[jj * 4 + e]);
  }
  const float tra0 = red4[0] + red4[1] + red4[2] + red4[3];  // read BEFORE (2)
  __syncthreads();   // (2) SYRK0 reads done; XcIH/red4 reusable

  // ---- src1: relu + center + pack
#pragma unroll
  for (int u = 0; u < 8; ++u) { ld0[u] = fmaxf(ld0[u], 0.f); ld1[u] = fmaxf(ld1[u], 0.f); }
  center_pack(ld0, ld1);
  __syncthreads();   // (3) XcIH(src1) + red4 ready

#pragma unroll
  for (int u = 0; u < 16; ++u) acc1[u] = 0.f;
  for (int ip = 0; ip < 31; ++ip) {
    const uint4 ju = *reinterpret_cast<const uint4*>(XcIH + ip * 64 + 4 * tj);
    const uint4 lu = *reinterpret_cast<const uint4*>(XcIH + ip * 64 + 4 * tl);
    const unsigned int jw[4] = {ju.x, ju.y, ju.z, ju.w};
    const unsigned int lw_[4] = {lu.x, lu.y, lu.z, lu.w};
#pragma unroll
    for (int jj = 0; jj < 4; ++jj)
#pragma unroll
      for (int e = 0; e < 4; ++e)
        acc1[jj * 4 + e] = DOT2(u2h(jw[jj]), u2h(lw_[e]), acc1[jj * 4 + e]);
  }
  const float tra1 = red4[0] + red4[1] + red4[2] + red4[3];

  // ---- combine + f16 store (full 64x64 coverage incl. zero pads)
  {
    const float s0 = 0.5f / tra0, s1 = 0.5f / tra1;
#pragma unroll
    for (int jj = 0; jj < 4; ++jj) {
      const int r = 4 * tj + jj;
      float e0 = acc0[jj * 4 + 0] * s0 + acc1[jj * 4 + 0] * s1;
      float e1 = acc0[jj * 4 + 1] * s0 + acc1[jj * 4 + 1] * s1;
      float e2 = acc0[jj * 4 + 2] * s0 + acc1[jj * 4 + 2] * s1;
      float e3 = acc0[jj * 4 + 3] * s0 + acc1[jj * 4 + 3] * s1;
      if (tj == tl) {
        if (jj == 0) e0 += 1e-5f;
        if (jj == 1) e1 += 1e-5f;
        if (jj == 2) e2 += 1e-5f;
        if (jj == 3) e3 += 1e-5f;
      }
      const int c0s = 4 * tl;
      if (r >= NC) { e0 = e1 = e2 = e3 = 0.f; }
      if (c0s + 2 >= NC) e2 = 0.f;
      if (c0s + 3 >= NC) e3 = 0.f;
      uint2 pk;
      pk.x = pk2u(e0, e1);
      pk.y = pk2u(e2, e3);
      *reinterpret_cast<uint2*>(comH + (size_t)bk * 4096 + r * 64 + c0s) = pk;
    }
  }

  // ---- block 0 epilogue: lwTH (f16 c-pairs), w1H (f16 o-pairs), row sums
  if (blockIdx.x == 0) {
    for (int t = tid; t < 2 * 32 * 64; t += 256) {
      const int brx = t >> 11, rem = t & 2047, cp = rem >> 6, o = rem & 63;
      const float* lwsrc = brx ? elin_w : hlin_w;
      float lo = 0.f, hi = 0.f;
      if (o < NC) {
        const int c = 2 * cp;
        if (c < NC)     lo = lwsrc[o * NC + c];
        if (c + 1 < NC) hi = lwsrc[o * NC + c + 1];
      }
      lwTHg[t] = pk2u(lo, hi);
    }
    for (int t = tid; t < NHID * 32; t += 256) {
      const int h = t >> 5, op = t & 31;
      const float lo = (2 * op < NC) ? att_w1[h * NC + 2 * op] : 0.f;
      const float hi = (2 * op + 1 < NC) ? att_w1[h * NC + 2 * op + 1] : 0.f;
      w1Hg[t] = pk2u(lo, hi);
    }
    if (tid < 64) {
      float sh = 0.f, se = 0.f;
      if (tid < NC) {
        for (int c = 0; c < NC; ++c) { sh += hlin_w[tid * NC + c]; se += elin_w[tid * NC + c]; }
      }
      rsumG[tid] = sh;
      rsumG[64 + tid] = se;
    }
  }
}

// =====================================================================
// Kernel B (v10): ONE 64-thread wave per (b,br); 4-row x 16-col tiles
// (rows rq,+16,+32,+48 x cols q*16..+15): per c-pair 4 b32 + 4 b128 for
// 64 dot2 = 1.11 LDS-cyc/dot2 (1.67x less than v9), and lw is read once
// per block instead of twice. Single wave -> NO barriers: single com
// buffer (CW=33), T14 reg-staging (global loads issued before GEMM,
// ds_write after — same-wave DS ops are in-order, WAR-safe).
// __launch_bounds__(64,2) caps VGPR at 256 -> 2 waves/SIMD resident.
// =====================================================================
__global__ __launch_bounds__(64, 2) void k_branch(
    const _Float16* __restrict__ comH, const unsigned int* __restrict__ lwTHg,
    const unsigned int* __restrict__ w1Hg, const float* __restrict__ rsumG,
    const float* __restrict__ hconv_w, const float* __restrict__ hconv_b,
    const float* __restrict__ hlin_b,
    const float* __restrict__ econv_w, const float* __restrict__ econv_b,
    const float* __restrict__ elin_b,
    const float* __restrict__ att_b1,  const float* __restrict__ att_w2,
    float* __restrict__ hiddenO, float* __restrict__ essentialO) {
  const int bid = (blockIdx.x & 7) * 256 + (blockIdx.x >> 3);  // XCD swizzle
  const int b = bid >> 1, br = bid & 1;

  const float* __restrict__ cw = br ? econv_w : hconv_w;
  const float* __restrict__ cb = br ? econv_b : hconv_b;
  const float* __restrict__ lb = br ? elin_b : hlin_b;
  float* __restrict__ outp = br ? essentialO : hiddenO;

  __shared__ __align__(16) unsigned int comHS[64 * CW];   // 8448 B single buf
  __shared__ __align__(16) unsigned int lwS[32 * 64];     // 8192 B [cp][o] f16x2
  __shared__ __align__(16) unsigned int w1HS[NHID * 32];  // 1280 B [h][op] f16x2
  __shared__ float rsumS[64], lbS[64];
  __shared__ float b1S[16], w2S[16], cwS[8], cbS[8];

  const int lane = threadIdx.x;            // 0..63, one wave
  const int rq = lane >> 2, q = lane & 3, o0 = q * 16;

  // ---- LDS fills (single wave: in-order DS, no barriers)
  {
    const uint4* src = reinterpret_cast<const uint4*>(lwTHg + br * 2048);
    uint4* dst = reinterpret_cast<uint4*>(lwS);
#pragma unroll
    for (int i = 0; i < 8; ++i) dst[lane + i * 64] = src[lane + i * 64];  // 512 uint4
  }
  for (int t = lane; t < NHID * 32; t += 64) w1HS[t] = w1Hg[t];
  rsumS[lane] = rsumG[br * 64 + lane];
  lbS[lane] = (lane < NC) ? lb[lane] : 0.f;
  if (lane < NHID) { b1S[lane] = att_b1[lane]; w2S[lane] = att_w2[lane]; }
  if (lane < NBAND) { cwS[lane] = cw[lane]; cbS[lane] = cb[lane]; }

  // ---- staging: band = 512 uint4; lane covers idx = i*64 + lane, i=0..7
  const uint4* gsrc = reinterpret_cast<const uint4*>(comH + (size_t)(b * NBAND) * 4096);
  uint4 pf[8];
  auto stage_issue = [&](int band) {
#pragma unroll
    for (int i = 0; i < 8; ++i) pf[i] = gsrc[band * 512 + i * 64 + lane];
  };
  auto stage_write = [&]() {
#pragma unroll
    for (int i = 0; i < 8; ++i) {
      const int idx = i * 64 + lane;          // uint4 index within band
      const int g = idx * 4;                  // u32 index
      const int row = g >> 5, col = g & 31;
      unsigned int* d = comHS + row * CW + col;
      d[0] = pf[i].x;
      d[1] = pf[i].y;
      d[2] = pf[i].z;
      d[3] = pf[i].w;
    }
  };

  f32x2 oacc2[4][8];
#pragma unroll
  for (int s = 0; s < 4; ++s)
#pragma unroll
    for (int u = 0; u < 8; ++u) oacc2[s][u] = (f32x2){0.f, 0.f};
  float denom[4] = {0.f, 0.f, 0.f, 0.f};
  float mrun[4] = {-1e30f, -1e30f, -1e30f, -1e30f};

  f32x2 accz2[4][8];   // [row s][o-pair u]

  // prologue: stage band 0
  stage_issue(0);
  stage_write();

#pragma unroll 1
  for (int kb = 0; kb < NBAND; ++kb) {
    // T14: issue next band's global loads before this band's GEMM
    if (kb < NBAND - 1) stage_issue(kb + 1);

    // ---- GEMM: 4 rows x 16 cols, fdot2 over 32 c-pairs
#pragma unroll
    for (int s = 0; s < 4; ++s)
#pragma unroll
      for (int u = 0; u < 8; ++u) accz2[s][u] = (f32x2){0.f, 0.f};
    {
      const uint4* lw4 = reinterpret_cast<const uint4*>(lwS);
#pragma unroll 4
      for (int cp = 0; cp < 32; ++cp) {
        const f16x2 a0 = u2h(comHS[rq * CW + cp]);
        const f16x2 a1 = u2h(comHS[(rq + 16) * CW + cp]);
        const f16x2 a2 = u2h(comHS[(rq + 32) * CW + cp]);
        const f16x2 a3 = u2h(comHS[(rq + 48) * CW + cp]);
        const uint4 wA = lw4[cp * 16 + 4 * q + 0];
        const uint4 wB = lw4[cp * 16 + 4 * q + 1];
        const uint4 wC = lw4[cp * 16 + 4 * q + 2];
        const uint4 wD = lw4[cp * 16 + 4 * q + 3];
        const unsigned int wu[16] = {wA.x, wA.y, wA.z, wA.w, wB.x, wB.y, wB.z, wB.w,
                                     wC.x, wC.y, wC.z, wC.w, wD.x, wD.y, wD.z, wD.w};
#pragma unroll
        for (int u = 0; u < 16; ++u) {
          const f16x2 wh = u2h(wu[u]);
          accz2[0][u >> 1][u & 1] = DOT2(a0, wh, accz2[0][u >> 1][u & 1]);
          accz2[1][u >> 1][u & 1] = DOT2(a1, wh, accz2[1][u >> 1][u & 1]);
          accz2[2][u >> 1][u & 1] = DOT2(a2, wh, accz2[2][u >> 1][u & 1]);
          accz2[3][u >> 1][u & 1] = DOT2(a3, wh, accz2[3][u >> 1][u & 1]);
        }
      }
    }

    // overwrite buffer with next band (in-order DS: lands after the reads)
    if (kb < NBAND - 1) stage_write();

    // ---- sigmoid in place -> z (packed)
    {
      const float ck = cwS[kb], dk = cbS[kb];
      const f32x2 ckv = {ck, ck}, dkv = {dk, dk};
      const f32x2* rs2 = reinterpret_cast<const f32x2*>(&rsumS[o0]);
      const f32x2* lb2 = reinterpret_cast<const f32x2*>(&lbS[o0]);
#pragma unroll
      for (int s = 0; s < 4; ++s)
#pragma unroll
        for (int u = 0; u < 8; ++u) {
          const f32x2 zv = FMA2(ckv, accz2[s][u], FMA2(dkv, rs2[u], lb2[u]));
          accz2[s][u][0] = 1.f / (1.f + __expf(-zv[0]));
          accz2[s][u][1] = 1.f / (1.f + __expf(-zv[1]));
        }
    }

    // ---- z -> f16 pairs for the fdot2 scorer
    unsigned int zh[4][8];
#pragma unroll
    for (int s = 0; s < 4; ++s)
#pragma unroll
      for (int u = 0; u < 8; ++u) zh[s][u] = pk2u(accz2[s][u][0], accz2[s][u][1]);

    // ---- scorer: per h-pair, all 4 row-sums xor-reduced over the 4
    // q-lanes; lane q evaluates both tanh for its row (rq + 16q).
    float sacc = 0.f;
#pragma unroll
    for (int t = 0; t < 5; ++t) {
      const int hA = 2 * t, hB = 2 * t + 1;
      const uint4 wa0 = *reinterpret_cast<const uint4*>(w1HS + hA * 32 + q * 8);
      const uint4 wa1 = *reinterpret_cast<const uint4*>(w1HS + hA * 32 + q * 8 + 4);
      const uint4 wb0 = *reinterpret_cast<const uint4*>(w1HS + hB * 32 + q * 8);
      const uint4 wb1 = *reinterpret_cast<const uint4*>(w1HS + hB * 32 + q * 8 + 4);
      const unsigned int wau[8] = {wa0.x, wa0.y, wa0.z, wa0.w, wa1.x, wa1.y, wa1.z, wa1.w};
      const unsigned int wbu[8] = {wb0.x, wb0.y, wb0.z, wb0.w, wb1.x, wb1.y, wb1.z, wb1.w};
      float pA[4] = {0.f, 0.f, 0.f, 0.f}, pB[4] = {0.f, 0.f, 0.f, 0.f};
#pragma unroll
      for (int u = 0; u < 8; ++u) {
        const f16x2 a = u2h(wau[u]), bb2 = u2h(wbu[u]);
#pragma unroll
        for (int s = 0; s < 4; ++s) {
          pA[s] = DOT2(u2h(zh[s][u]), a, pA[s]);
          pB[s] = DOT2(u2h(zh[s][u]), bb2, pB[s]);
        }
      }
#pragma unroll
      for (int s = 0; s < 4; ++s) {
        pA[s] += __shfl_xor(pA[s], 1, 64); pA[s] += __shfl_xor(pA[s], 2, 64);
        pB[s] += __shfl_xor(pB[s], 1, 64); pB[s] += __shfl_xor(pB[s], 2, 64);
      }
      const float pmA = (q == 0) ? pA[0] : (q == 1) ? pA[1] : (q == 2) ? pA[2] : pA[3];
      const float pmB = (q == 0) ? pB[0] : (q == 1) ? pB[1] : (q == 2) ? pB[2] : pB[3];
      const float exA = __expf(2.f * (pmA + b1S[hA]));
      const float exB = __expf(2.f * (pmB + b1S[hB]));
      sacc += w2S[hA] * (1.f - 2.f / (exA + 1.f));
      sacc += w2S[hB] * (1.f - 2.f / (exB + 1.f));
    }
    // sacc(lane q) = score[row rq + 16q]; broadcast within 4-lane group
    const int gbase = lane & 60;
    float sc[4];
#pragma unroll
    for (int s = 0; s < 4; ++s) sc[s] = __shfl(sacc, gbase + s, 64);

    // ---- online softmax accumulate (per row, packed)
#pragma unroll
    for (int s = 0; s < 4; ++s) {
      const float nm = fmaxf(mrun[s], sc[s]);
      const float f = __expf(mrun[s] - nm), e = __expf(sc[s] - nm);
      denom[s] = denom[s] * f + e;
      const f32x2 fv = {f, f}, ev = {e, e};
#pragma unroll
      for (int u = 0; u < 8; ++u) oacc2[s][u] = FMA2(oacc2[s][u], fv, ev * accz2[s][u]);
      mrun[s] = nm;
    }
  }

  // ---- store (f32x2: row base 62 floats -> 8B aligned)
#pragma unroll
  for (int s = 0; s < 4; ++s) {
    const int r = rq + 16 * s;
    if (r < NC) {
      const float inv = 1.f / denom[s];
      const f32x2 invv = {inv, inv};
      float* rowp = outp + (size_t)b * (NC * NC) + r * NC + o0;
      const int ne = (q < 3) ? 8 : 7;   // cols 48..61 for q==3
#pragma unroll
      for (int e = 0; e < 8; ++e)
        if (e < ne)
          *reinterpret_cast<f32x2*>(rowp + 2 * e) = oacc2[s][e] * invv;
    }
  }
}

// =====================================================================
// Kernel C: Chebyshev GCN (both adjacencies, shared de@gc_w), feature,
// and the 992->62 FC. wnorm == 1 exactly; relu((h+e)/2) no-op on relu'd h,e.
// =====================================================================
__global__ __launch_bounds__(256) void k_cheb_fc(
    const float* __restrict__ de, const float* __restrict__ hidden,
    const float* __restrict__ essential, const float* __restrict__ gc_w,
    const float* __restrict__ gc_b, const float* __restrict__ fc_w,
    const float* __restrict__ fc_b, float* __restrict__ zmat) {
  const int b = blockIdx.x;
  __shared__ float hidS[NC * NC], essS[NC * NC];
  __shared__ float t0S[NC * NOUT], t1S[NC * NOUT];
  __shared__ float featS[NC * NOUT];
  __shared__ float deS[NC * NBAND];
  __shared__ float red2[256];
  const int tid = threadIdx.x;

  for (int t = tid; t < NC * NBAND; t += 256) deS[t] = de[b * NC * NBAND + t];
  for (int t = tid; t < NC * NC; t += 256) {
    hidS[t] = hidden[b * NC * NC + t];
    essS[t] = essential[b * NC * NC + t];
  }
  __syncthreads();
  for (int t = tid; t < NC * NOUT; t += 256) {
    const int i = t / NOUT, f = t % NOUT;
    float a0 = gc_b[f];
    float a1 = 0.f;
#pragma unroll
    for (int qq = 0; qq < NBAND; ++qq) {
      const float d = deS[i * NBAND + qq];
      a0 += d * gc_w[qq * NOUT + f];
      a1 += d * gc_w[(NBAND + qq) * NOUT + f];
    }
    t0S[t] = a0;
    t1S[t] = a1;
  }
  __syncthreads();
  for (int t = tid; t < NC * NOUT; t += 256) {
    const int i = t / NOUT, f = t % NOUT;
    float sh = 0.f, se = 0.f;
    for (int jj = 0; jj < NC; ++jj) {
      const float t1 = t1S[jj * NOUT + f];
      sh += hidS[i * NC + jj] * t1;
      se += essS[i * NC + jj] * t1;
    }
    const float gb1 = gc_b[NOUT + f];
    const float h = fmaxf(t0S[t] + sh + gb1, 0.f);
    const float e = fmaxf(t0S[t] + se + gb1, 0.f);
    featS[t] = 0.5f * (h + e);
  }
  __syncthreads();
  {
    const int n = tid >> 2, qq = tid & 3;
    float p = 0.f;
    if (n < NC) {
      const float* fw = fc_w + n * (NC * NOUT) + qq * 248;
      const float* fs = featS + qq * 248;
      for (int m = 0; m < 248; ++m) p += fs[m] * fw[m];
    }
    red2[tid] = p;
    __syncthreads();
    if (tid < NC) {
      const float z = red2[tid * 4] + red2[tid * 4 + 1] + red2[tid * 4 + 2] + red2[tid * 4 + 3] + fc_b[tid];
      zmat[b * NC + tid] = z;
    }
  }
}

// =====================================================================
// Kernel D1: batch-norm statistics (training-mode batch stats, ddof=0).
// =====================================================================
__global__ __launch_bounds__(256) void k_bnstats(
    const float* __restrict__ zmat, const float* __restrict__ bn_g,
    const float* __restrict__ bn_b, float* __restrict__ bnp) {
  const int n = blockIdx.x;
  __shared__ float rs[256], rq[256];
  const int tid = threadIdx.x;
  float s = 0.f, sq = 0.f;
  for (int r = tid; r < NB; r += 256) {
    const float v = zmat[r * NC + n];
    s += v;
    sq += v * v;
  }
  rs[tid] = s; rq[tid] = sq;
  __syncthreads();
  for (int st = 128; st > 0; st >>= 1) {
    if (tid < st) { rs[tid] += rs[tid + st]; rq[tid] += rq[tid + st]; }
    __syncthreads();
  }
  if (tid == 0) {
    const float mean = rs[0] * (1.f / NB);
    const float var = rq[0] * (1.f / NB) - mean * mean;
    const float sc = bn_g[n] * rsqrtf(var + 1e-5f);
    bnp[2 * n] = sc;
    bnp[2 * n + 1] = bn_b[n] - mean * sc;
  }
}

// =====================================================================
// Kernel D2: apply BN + sigmoid -> output1; 62->2 FC -> output.
// =====================================================================
__global__ __launch_bounds__(64) void k_bn_out(
    const float* __restrict__ zmat, const float* __restrict__ bnp,
    const float* __restrict__ fc4_w, const float* __restrict__ fc4_b,
    float* __restrict__ out) {
  const int b = blockIdx.x;
  const int lane = threadIdx.x;
  float o1 = 0.f;
  if (lane < NC) {
    float z = zmat[b * NC + lane];
    z = z * bnp[2 * lane] + bnp[2 * lane + 1];
    o1 = 1.f / (1.f + __expf(-z));
    out[b * NC + lane] = o1;
  }
  float p0 = (lane < NC) ? o1 * fc4_w[lane] : 0.f;
  float p1 = (lane < NC) ? o1 * fc4_w[NC + lane] : 0.f;
#pragma unroll
  for (int off = 32; off > 0; off >>= 1) {
    p0 += __shfl_down(p0, off, 64);
    p1 += __shfl_down(p1, off, 64);
  }
  if (lane == 0) {
    out[NB * NC + b * 2 + 0] = p0 + fc4_b[0];
    out[NB * NC + b * 2 + 1] = p1 + fc4_b[1];
  }
}

extern "C" void kernel_launch(void* const* d_in, const int* in_sizes, int n_in,
                              void* d_out, int out_size, void* d_ws, size_t ws_size,
                              hipStream_t stream) {
  const float* de      = (const float*)d_in[0];
  const float* pcc     = (const float*)d_in[1];
  const float* Aadj    = (const float*)d_in[2];
  // d_in[3] conv_w, d_in[4] conv_b: dead (gate cancels in trace-normalized SPD)
  const float* hconv_w = (const float*)d_in[5];
  const float* hconv_b = (const float*)d_in[6];
  const float* hlin_w  = (const float*)d_in[7];
  const float* hlin_b  = (const float*)d_in[8];
  const float* econv_w = (const float*)d_in[9];
  const float* econv_b = (const float*)d_in[10];
  const float* elin_w  = (const float*)d_in[11];
  const float* elin_b  = (const float*)d_in[12];
  const float* att_w1  = (const float*)d_in[13];
  const float* att_b1  = (const float*)d_in[14];
  const float* att_w2  = (const float*)d_in[15];
  const float* gc_w    = (const float*)d_in[16];
  const float* gc_b    = (const float*)d_in[17];
  // d_in[18] wpar: wnorm = exp(w)/exp(w) = 1 exactly for 1-element wpar
  const float* fc_w    = (const float*)d_in[19];
  const float* fc_b    = (const float*)d_in[20];
  const float* bn_g    = (const float*)d_in[21];
  const float* bn_b    = (const float*)d_in[22];
  const float* fc4_w   = (const float*)d_in[23];
  const float* fc4_b   = (const float*)d_in[24];

  float* ws        = (float*)d_ws;
  _Float16* comH   = (_Float16*)ws;                      // 5120*4096 halves = 41.9 MB
  float* hidden    = ws + 10485760;                      //  3,936,256 floats
  float* essential = hidden + (size_t)NB * NC * NC;
  float* zmat      = essential + (size_t)NB * NC * NC;   //     63,488
  float* bnp       = zmat + (size_t)NB * NC;             //        128
  unsigned int* lwTHg = (unsigned int*)(bnp + 128);      //      4,096 u32
  unsigned int* w1Hg  = lwTHg + 4096;                    //        320 u32
  float* rsumG     = (float*)(w1Hg + 512);               //        128
  // total ~74 MB of workspace

  k_spd<<<NB * NBAND, 256, 0, stream>>>(pcc, Aadj, hlin_w, elin_w, att_w1,
                                        comH, lwTHg, w1Hg, rsumG);
  k_branch<<<NB * 2, 64, 0, stream>>>(comH, lwTHg, w1Hg, rsumG,
      hconv_w, hconv_b, hlin_b,
      econv_w, econv_b, elin_b,
      att_b1, att_w2, hidden, essential);
  k_cheb_fc<<<NB, 256, 0, stream>>>(de, hidden, essential, gc_w, gc_b, fc_w, fc_b, zmat);
  k_bnstats<<<NC, 256, 0, stream>>>(zmat, bn_g, bn_b, bnp);
  k_bn_out<<<NB, 64, 0, stream>>>(zmat, bnp, fc4_w, fc4_b, (float*)d_out);
}

// Round 12
// 186.530 us; speedup vs baseline: 1.3851x; 1.3851x over previous
//
#include <hip/hip_runtime.h>
#include <math.h>

#define NB    1024
#define NC    62
#define NBAND 5
#define NOUT  16
#define NHID  10
#define ZSTR  68   // zS row stride in f16

typedef __attribute__((ext_vector_type(2))) float f32x2;
typedef __attribute__((ext_vector_type(4))) float f32x4;
typedef __attribute__((ext_vector_type(2))) _Float16 f16x2;
typedef __attribute__((ext_vector_type(8))) _Float16 f16x8;
typedef __attribute__((ext_vector_type(2))) __fp16 fp16v2;   // cvt_pkrtz result type
#define FMA2(a, b, c) __builtin_elementwise_fma((a), (b), (c))
#define DOT2(a, b, c) __builtin_amdgcn_fdot2((a), (b), (c), false)

__device__ __forceinline__ f16x2 u2h(unsigned int u) { return __builtin_bit_cast(f16x2, u); }
__device__ __forceinline__ unsigned int pk2u(float x, float y) {
  const fp16v2 v = __builtin_amdgcn_cvt_pkrtz(x, y);
  return __builtin_bit_cast(unsigned int, v);
}

// =====================================================================
// Kernel A: gate-cancelled SPD (round-10 structure).
//   com[b,k] = 0.5*(N(relu(pcc_t)) + N(relu(A))) + 1e-5*I, f16 output.
// Epilogue change: emits lwHg ROW-MAJOR f16 [br][o][c] (zero-padded
// 64x64) for k_branch's MFMA B-operand, plus w1Hg o-pairs and rsumG.
// =====================================================================
__global__ __launch_bounds__(256) void k_spd(
    const float* __restrict__ pcc, const float* __restrict__ Aadj,
    const float* __restrict__ hlin_w, const float* __restrict__ elin_w,
    const float* __restrict__ att_w1,
    _Float16* __restrict__ comH, unsigned int* __restrict__ lwHg,
    unsigned int* __restrict__ w1Hg, float* __restrict__ rsumG) {
  const int bk = (blockIdx.x & 7) * 640 + (blockIdx.x >> 3);  // XCD swizzle, 5120%8==0
  const int b = bk / NBAND, k = bk % NBAND;
  __shared__ __align__(16) unsigned int XcIH[31 * 64];   // 7936 B, f16x2 [ip][c]
  __shared__ float red4[4];
  const int tid = threadIdx.x;
  const int wave = tid >> 6, lane = tid & 63;
  const int p = tid >> 3, q8 = tid & 7, c0 = q8 * 8;
  const bool act = (p < 31);
  const int r0 = 2 * p, r1 = r0 + 1;

  float ld0[8], ld1[8];

  auto center_pack = [&](float (&a0)[8], float (&a1)[8]) -> void {
    float s0 = 0.f, s1 = 0.f;
#pragma unroll
    for (int u = 0; u < 8; ++u) { s0 += a0[u]; s1 += a1[u]; }
    s0 += __shfl_xor(s0, 1, 64); s0 += __shfl_xor(s0, 2, 64); s0 += __shfl_xor(s0, 4, 64);
    s1 += __shfl_xor(s1, 1, 64); s1 += __shfl_xor(s1, 2, 64); s1 += __shfl_xor(s1, 4, 64);
    const float m0 = s0 * (1.f / NC), m1 = s1 * (1.f / NC);
    float sq = 0.f;
    if (act) {
      unsigned int pk[8];
#pragma unroll
      for (int u = 0; u < 8; ++u) {
        const int c = c0 + u;
        const float cv0 = (c < NC) ? (a0[u] - m0) : 0.f;
        const float cv1 = (c < NC) ? (a1[u] - m1) : 0.f;
        sq += cv0 * cv0 + cv1 * cv1;
        pk[u] = pk2u(cv0, cv1);
      }
      uint4* d = reinterpret_cast<uint4*>(XcIH + p * 64 + c0);
      d[0] = make_uint4(pk[0], pk[1], pk[2], pk[3]);
      d[1] = make_uint4(pk[4], pk[5], pk[6], pk[7]);
    }
#pragma unroll
    for (int off = 1; off < 64; off <<= 1) sq += __shfl_xor(sq, off, 64);
    if (lane == 0) red4[wave] = sq;
  };

  // ---- src0 = relu(pcc[b,:,:,k]) : stride-5 scalar loads
#pragma unroll
  for (int u = 0; u < 8; ++u) { ld0[u] = 0.f; ld1[u] = 0.f; }
  if (act) {
    const float* s0p = pcc + ((size_t)(b * NC + r0) * NC + c0) * NBAND + k;
    const float* s1p = pcc + ((size_t)(b * NC + r1) * NC + c0) * NBAND + k;
#pragma unroll
    for (int u = 0; u < 8; ++u) {
      if (c0 + u < NC) {
        ld0[u] = fmaxf(s0p[u * NBAND], 0.f);
        ld1[u] = fmaxf(s1p[u * NBAND], 0.f);
      }
    }
  }
  center_pack(ld0, ld1);

  // prefetch src1 = Aadj rows
#pragma unroll
  for (int u = 0; u < 8; ++u) { ld0[u] = 0.f; ld1[u] = 0.f; }
  if (act) {
    const float* a0p = Aadj + ((size_t)(b * NBAND + k) * NC + r0) * NC + c0;
    const float* a1p = Aadj + ((size_t)(b * NBAND + k) * NC + r1) * NC + c0;
#pragma unroll
    for (int e = 0; e < 4; ++e) {
      const int c = c0 + 2 * e;
      if (c + 1 < NC) {
        const float2 v0 = *reinterpret_cast<const float2*>(a0p + 2 * e);
        const float2 v1 = *reinterpret_cast<const float2*>(a1p + 2 * e);
        ld0[2 * e] = v0.x; ld0[2 * e + 1] = v0.y;
        ld1[2 * e] = v1.x; ld1[2 * e + 1] = v1.y;
      } else if (c < NC) {
        ld0[2 * e] = a0p[2 * e];
        ld1[2 * e] = a1p[2 * e];
      }
    }
  }
  __syncthreads();   // (1) XcIH(src0) + red4 ready

  // ---- SYRK0: thread (tj,tl) owns G[4tj..][4tl..]; fdot2 over i-pairs
  const int tj = tid >> 4, tl = tid & 15;
  float acc0[16], acc1[16];
#pragma unroll
  for (int u = 0; u < 16; ++u) acc0[u] = 0.f;
  for (int ip = 0; ip < 31; ++ip) {
    const uint4 ju = *reinterpret_cast<const uint4*>(XcIH + ip * 64 + 4 * tj);
    const uint4 lu = *reinterpret_cast<const uint4*>(XcIH + ip * 64 + 4 * tl);
    const unsigned int jw[4] = {ju.x, ju.y, ju.z, ju.w};
    const unsigned int lw_[4] = {lu.x, lu.y, lu.z, lu.w};
#pragma unroll
    for (int jj = 0; jj < 4; ++jj)
#pragma unroll
      for (int e = 0; e < 4; ++e)
        acc0[jj * 4 + e] = DOT2(u2h(jw[jj]), u2h(lw_[e]), acc0[jj * 4 + e]);
  }
  const float tra0 = red4[0] + red4[1] + red4[2] + red4[3];  // read BEFORE (2)
  __syncthreads();   // (2) SYRK0 reads done; XcIH/red4 reusable

  // ---- src1: relu + center + pack
#pragma unroll
  for (int u = 0; u < 8; ++u) { ld0[u] = fmaxf(ld0[u], 0.f); ld1[u] = fmaxf(ld1[u], 0.f); }
  center_pack(ld0, ld1);
  __syncthreads();   // (3) XcIH(src1) + red4 ready

#pragma unroll
  for (int u = 0; u < 16; ++u) acc1[u] = 0.f;
  for (int ip = 0; ip < 31; ++ip) {
    const uint4 ju = *reinterpret_cast<const uint4*>(XcIH + ip * 64 + 4 * tj);
    const uint4 lu = *reinterpret_cast<const uint4*>(XcIH + ip * 64 + 4 * tl);
    const unsigned int jw[4] = {ju.x, ju.y, ju.z, ju.w};
    const unsigned int lw_[4] = {lu.x, lu.y, lu.z, lu.w};
#pragma unroll
    for (int jj = 0; jj < 4; ++jj)
#pragma unroll
      for (int e = 0; e < 4; ++e)
        acc1[jj * 4 + e] = DOT2(u2h(jw[jj]), u2h(lw_[e]), acc1[jj * 4 + e]);
  }
  const float tra1 = red4[0] + red4[1] + red4[2] + red4[3];

  // ---- combine + f16 store (full 64x64 coverage incl. zero pads)
  {
    const float s0 = 0.5f / tra0, s1 = 0.5f / tra1;
#pragma unroll
    for (int jj = 0; jj < 4; ++jj) {
      const int r = 4 * tj + jj;
      float e0 = acc0[jj * 4 + 0] * s0 + acc1[jj * 4 + 0] * s1;
      float e1 = acc0[jj * 4 + 1] * s0 + acc1[jj * 4 + 1] * s1;
      float e2 = acc0[jj * 4 + 2] * s0 + acc1[jj * 4 + 2] * s1;
      float e3 = acc0[jj * 4 + 3] * s0 + acc1[jj * 4 + 3] * s1;
      if (tj == tl) {
        if (jj == 0) e0 += 1e-5f;
        if (jj == 1) e1 += 1e-5f;
        if (jj == 2) e2 += 1e-5f;
        if (jj == 3) e3 += 1e-5f;
      }
      const int c0s = 4 * tl;
      if (r >= NC) { e0 = e1 = e2 = e3 = 0.f; }
      if (c0s + 2 >= NC) e2 = 0.f;
      if (c0s + 3 >= NC) e3 = 0.f;
      uint2 pk;
      pk.x = pk2u(e0, e1);
      pk.y = pk2u(e2, e3);
      *reinterpret_cast<uint2*>(comH + (size_t)bk * 4096 + r * 64 + c0s) = pk;
    }
  }

  // ---- block 0 epilogue: lwHg row-major f16 [br][o][c], w1H, row sums
  if (blockIdx.x == 0) {
    for (int t = tid; t < 2 * 64 * 32; t += 256) {
      const int brx = t >> 11, rem = t & 2047, o = rem >> 5, cp = rem & 31;
      const float* lwsrc = brx ? elin_w : hlin_w;
      float lo = 0.f, hi = 0.f;
      if (o < NC) {
        const int c = 2 * cp;
        if (c < NC)     lo = lwsrc[o * NC + c];
        if (c + 1 < NC) hi = lwsrc[o * NC + c + 1];
      }
      lwHg[t] = pk2u(lo, hi);   // [br][o][c-pair] row-major
    }
    for (int t = tid; t < NHID * 32; t += 256) {
      const int h = t >> 5, op = t & 31;
      const float lo = (2 * op < NC) ? att_w1[h * NC + 2 * op] : 0.f;
      const float hi = (2 * op + 1 < NC) ? att_w1[h * NC + 2 * op + 1] : 0.f;
      w1Hg[t] = pk2u(lo, hi);
    }
    if (tid < 64) {
      float sh = 0.f, se = 0.f;
      if (tid < NC) {
        for (int c = 0; c < NC; ++c) { sh += hlin_w[tid * NC + c]; se += elin_w[tid * NC + c]; }
      }
      rsumG[tid] = sh;
      rsumG[64 + tid] = se;
    }
  }
}

// =====================================================================
// Kernel B (v11, MFMA): 256 threads = 4 waves per (b,br); wave w owns
// output rows 16w..16w+15 (strip). z-GEMM = 2x mfma_f32_16x16x32_f16
// per n-tile: A = com strip rows (XOR-swizzled wave-private LDS, T14
// reg-staged), B = lw held in REGISTERS (8 frags, band-invariant).
// k-permutation of the assumed fragment layout cancels (A and B use the
// same self-chosen k offsets); M/N maps = l&15; C/D = guide-verified.
// Epilogue in C-layout regs; scorer via per-wave zS round-trip (fdot2 on
// o-pair f16 w1). Zero barriers in the band loop (all LDS wave-private).
// =====================================================================
__global__ __launch_bounds__(256, 2) void k_branch(
    const _Float16* __restrict__ comH, const unsigned int* __restrict__ lwHg,
    const unsigned int* __restrict__ w1Hg, const float* __restrict__ rsumG,
    const float* __restrict__ hconv_w, const float* __restrict__ hconv_b,
    const float* __restrict__ hlin_b,
    const float* __restrict__ econv_w, const float* __restrict__ econv_b,
    const float* __restrict__ elin_b,
    const float* __restrict__ att_b1,  const float* __restrict__ att_w2,
    float* __restrict__ hiddenO, float* __restrict__ essentialO) {
  const int bid = (blockIdx.x & 7) * 256 + (blockIdx.x >> 3);  // XCD swizzle
  const int b = bid >> 1, br = bid & 1;

  const float* __restrict__ cw = br ? econv_w : hconv_w;
  const float* __restrict__ cb = br ? econv_b : hconv_b;
  const float* __restrict__ lb = br ? elin_b : hlin_b;
  float* __restrict__ outp = br ? essentialO : hiddenO;

  __shared__ __align__(16) unsigned int comS[64 * 32];     // 8 KB, XOR-swizzled
  __shared__ __align__(16) _Float16 zS[4][16 * ZSTR];      // 8.7 KB, per-wave
  __shared__ __align__(16) unsigned int w1S[NHID * 32];    // o-pair f16
  __shared__ float scoreS[4][16];
  __shared__ float b1S[16], w2S[16], cwS[8], cbS[8];

  const int tid = threadIdx.x;
  const int w = tid >> 6, lane = tid & 63;
  const int mrow = lane & 15;       // A-row within strip / C col-within-tile
  const int g = lane >> 4;          // k-group / C row-group

  // ---- param fills (block-wide -> one barrier)
  for (int t = tid; t < NHID * 32; t += 256) w1S[t] = w1Hg[t];
  if (tid < NHID) { b1S[tid] = att_b1[tid]; w2S[tid] = att_w2[tid]; }
  if (tid < NBAND) { cwS[tid] = cw[tid]; cbS[tid] = cb[tid]; }

  // ---- B-frags in registers (band-invariant): B[s][n], col = 16n+mrow
  f16x8 Bf[2][4];
  float rsumR[4], lbR[4];
#pragma unroll
  for (int n = 0; n < 4; ++n) {
    const int col = 16 * n + mrow;
    rsumR[n] = rsumG[br * 64 + col];
    lbR[n] = (col < NC) ? lb[col] : 0.f;
#pragma unroll
    for (int s = 0; s < 2; ++s) {
      const uint4 v = *reinterpret_cast<const uint4*>(lwHg + br * 2048 + col * 32 + s * 16 + g * 4);
      Bf[s][n] = __builtin_bit_cast(f16x8, v);
    }
  }
  __syncthreads();   // w1S/b1S/w2S/cwS/cbS visible to all waves

  // ---- staging: wave w stages ITS strip rows 16w..16w+15 (128 uint4).
  // lane covers idx = w*128 + lane + {0,64}; row = 16w + (idx&127)>>3.
  const uint4* gsrc = reinterpret_cast<const uint4*>(comH + (size_t)(b * NBAND) * 4096);
  uint4 pf[2];
  auto stage_issue = [&](int band) {
#pragma unroll
    for (int i = 0; i < 2; ++i) pf[i] = gsrc[band * 512 + w * 128 + i * 64 + lane];
  };
  auto stage_write = [&]() {
#pragma unroll
    for (int i = 0; i < 2; ++i) {
      const int idx = i * 64 + lane;          // within strip: 0..127
      const int row = 16 * w + (idx >> 3), slot = idx & 7;
      const int sb = (slot * 16) ^ ((row & 7) << 4);   // swizzled byte in row
      *reinterpret_cast<uint4*>(comS + row * 32 + sb / 4) = pf[i];
    }
  };

  // A-frag read (kstep s): row = 16w + mrow, byte off = (64s+16g) ^ swz
  auto a_frag = [&](int s) -> f16x8 {
    const int row = 16 * w + mrow;
    const int sb = (64 * s + 16 * g) ^ ((row & 7) << 4);
    return __builtin_bit_cast(f16x8, *reinterpret_cast<const uint4*>(comS + row * 32 + sb / 4));
  };

  stage_issue(0);
  stage_write();

  f32x4 oacc[4];
#pragma unroll
  for (int n = 0; n < 4; ++n) oacc[n] = (f32x4){0.f, 0.f, 0.f, 0.f};
  float denom[4] = {0.f, 0.f, 0.f, 0.f};
  float mrun[4] = {-1e30f, -1e30f, -1e30f, -1e30f};

  _Float16* zSw = &zS[4 > 0 ? w : 0][0];   // wave-private
  const int rowz = lane >> 2, qz = lane & 3;   // scorer mapping

#pragma unroll 1
  for (int kb = 0; kb < NBAND; ++kb) {
    if (kb < NBAND - 1) stage_issue(kb + 1);   // T14: issue early

    // ---- MFMA GEMM: acc[n] = A(strip) x B[n], K=64 in 2 steps
    const f16x8 A0 = a_frag(0);
    const f16x8 A1 = a_frag(1);
    f32x4 acc[4];
#pragma unroll
    for (int n = 0; n < 4; ++n) {
      acc[n] = __builtin_amdgcn_mfma_f32_16x16x32_f16(A0, Bf[0][n], (f32x4){0.f, 0.f, 0.f, 0.f}, 0, 0, 0);
      acc[n] = __builtin_amdgcn_mfma_f32_16x16x32_f16(A1, Bf[1][n], acc[n], 0, 0, 0);
    }

    if (kb < NBAND - 1) stage_write();   // in-order DS: lands after A reads

    // ---- sigmoid in C-layout regs; write z to wave-private zS (f16)
    const float ck = cwS[kb], dk = cbS[kb];
#pragma unroll
    for (int n = 0; n < 4; ++n) {
      const float base = dk * rsumR[n] + lbR[n];
#pragma unroll
      for (int reg = 0; reg < 4; ++reg) {
        const float zv = 1.f / (1.f + __expf(-(ck * acc[n][reg] + base)));
        acc[n][reg] = zv;
        zSw[(4 * g + reg) * ZSTR + 16 * n + mrow] = (_Float16)zv;
      }
    }

    // ---- scorer over zS rows (v9 pattern): row = lane>>2, q = lane&3
    {
      const _Float16* zr = zSw + rowz * ZSTR + qz * 16;
      unsigned int zh[8];
#pragma unroll
      for (int j = 0; j < 4; ++j) {
        const uint2 v = *reinterpret_cast<const uint2*>(zr + 4 * j);  // 8B-aligned
        zh[2 * j] = v.x;
        zh[2 * j + 1] = v.y;
      }
      float sacc = 0.f;
#pragma unroll
      for (int t = 0; t < 5; ++t) {
        const int hA = 2 * t, hB = 2 * t + 1;
        const uint4 wa0 = *reinterpret_cast<const uint4*>(w1S + hA * 32 + qz * 8);
        const uint4 wa1 = *reinterpret_cast<const uint4*>(w1S + hA * 32 + qz * 8 + 4);
        const uint4 wb0 = *reinterpret_cast<const uint4*>(w1S + hB * 32 + qz * 8);
        const uint4 wb1 = *reinterpret_cast<const uint4*>(w1S + hB * 32 + qz * 8 + 4);
        const unsigned int wau[8] = {wa0.x, wa0.y, wa0.z, wa0.w, wa1.x, wa1.y, wa1.z, wa1.w};
        const unsigned int wbu[8] = {wb0.x, wb0.y, wb0.z, wb0.w, wb1.x, wb1.y, wb1.z, wb1.w};
        float pA = 0.f, pB = 0.f;
#pragma unroll
        for (int u = 0; u < 8; ++u) {
          pA = DOT2(u2h(zh[u]), u2h(wau[u]), pA);
          pB = DOT2(u2h(zh[u]), u2h(wbu[u]), pB);
        }
        pA += __shfl_xor(pA, 1, 64); pA += __shfl_xor(pA, 2, 64);
        pB += __shfl_xor(pB, 1, 64); pB += __shfl_xor(pB, 2, 64);
        const float exA = __expf(2.f * (pA + b1S[hA]));
        const float exB = __expf(2.f * (pB + b1S[hB]));
        sacc += w2S[hA] * (1.f - 2.f / (exA + 1.f));
        sacc += w2S[hB] * (1.f - 2.f / (exB + 1.f));
      }
      if (qz == 0) scoreS[w][rowz] = sacc;
    }

    // ---- online softmax on C-layout accs (rows 4g+reg)
#pragma unroll
    for (int reg = 0; reg < 4; ++reg) {
      const float sc = scoreS[w][4 * g + reg];     // in-order after write
      const float nm = fmaxf(mrun[reg], sc);
      const float f = __expf(mrun[reg] - nm), e = __expf(sc - nm);
      denom[reg] = denom[reg] * f + e;
#pragma unroll
      for (int n = 0; n < 4; ++n)
        oacc[n][reg] = oacc[n][reg] * f + e * acc[n][reg];
      mrun[reg] = nm;
    }
  }

  // ---- store: r = 16w + 4g + reg, col = 16n + mrow
#pragma unroll
  for (int reg = 0; reg < 4; ++reg) {
    const int r = 16 * w + 4 * g + reg;
    if (r < NC) {
      const float inv = 1.f / denom[reg];
#pragma unroll
      for (int n = 0; n < 4; ++n) {
        const int col = 16 * n + mrow;
        if (col < NC) outp[(size_t)b * (NC * NC) + r * NC + col] = oacc[n][reg] * inv;
      }
    }
  }
}

// =====================================================================
// Kernel C: Chebyshev GCN + feature + 992->62 FC (unchanged).
// =====================================================================
__global__ __launch_bounds__(256) void k_cheb_fc(
    const float* __restrict__ de, const float* __restrict__ hidden,
    const float* __restrict__ essential, const float* __restrict__ gc_w,
    const float* __restrict__ gc_b, const float* __restrict__ fc_w,
    const float* __restrict__ fc_b, float* __restrict__ zmat) {
  const int b = blockIdx.x;
  __shared__ float hidS[NC * NC], essS[NC * NC];
  __shared__ float t0S[NC * NOUT], t1S[NC * NOUT];
  __shared__ float featS[NC * NOUT];
  __shared__ float deS[NC * NBAND];
  __shared__ float red2[256];
  const int tid = threadIdx.x;

  for (int t = tid; t < NC * NBAND; t += 256) deS[t] = de[b * NC * NBAND + t];
  for (int t = tid; t < NC * NC; t += 256) {
    hidS[t] = hidden[b * NC * NC + t];
    essS[t] = essential[b * NC * NC + t];
  }
  __syncthreads();
  for (int t = tid; t < NC * NOUT; t += 256) {
    const int i = t / NOUT, f = t % NOUT;
    float a0 = gc_b[f];
    float a1 = 0.f;
#pragma unroll
    for (int qq = 0; qq < NBAND; ++qq) {
      const float d = deS[i * NBAND + qq];
      a0 += d * gc_w[qq * NOUT + f];
      a1 += d * gc_w[(NBAND + qq) * NOUT + f];
    }
    t0S[t] = a0;
    t1S[t] = a1;
  }
  __syncthreads();
  for (int t = tid; t < NC * NOUT; t += 256) {
    const int i = t / NOUT, f = t % NOUT;
    float sh = 0.f, se = 0.f;
    for (int jj = 0; jj < NC; ++jj) {
      const float t1 = t1S[jj * NOUT + f];
      sh += hidS[i * NC + jj] * t1;
      se += essS[i * NC + jj] * t1;
    }
    const float gb1 = gc_b[NOUT + f];
    const float h = fmaxf(t0S[t] + sh + gb1, 0.f);
    const float e = fmaxf(t0S[t] + se + gb1, 0.f);
    featS[t] = 0.5f * (h + e);
  }
  __syncthreads();
  {
    const int n = tid >> 2, qq = tid & 3;
    float p = 0.f;
    if (n < NC) {
      const float* fw = fc_w + n * (NC * NOUT) + qq * 248;
      const float* fs = featS + qq * 248;
      for (int m = 0; m < 248; ++m) p += fs[m] * fw[m];
    }
    red2[tid] = p;
    __syncthreads();
    if (tid < NC) {
      const float z = red2[tid * 4] + red2[tid * 4 + 1] + red2[tid * 4 + 2] + red2[tid * 4 + 3] + fc_b[tid];
      zmat[b * NC + tid] = z;
    }
  }
}

// =====================================================================
// Kernel D1: batch-norm statistics (unchanged).
// =====================================================================
__global__ __launch_bounds__(256) void k_bnstats(
    const float* __restrict__ zmat, const float* __restrict__ bn_g,
    const float* __restrict__ bn_b, float* __restrict__ bnp) {
  const int n = blockIdx.x;
  __shared__ float rs[256], rq[256];
  const int tid = threadIdx.x;
  float s = 0.f, sq = 0.f;
  for (int r = tid; r < NB; r += 256) {
    const float v = zmat[r * NC + n];
    s += v;
    sq += v * v;
  }
  rs[tid] = s; rq[tid] = sq;
  __syncthreads();
  for (int st = 128; st > 0; st >>= 1) {
    if (tid < st) { rs[tid] += rs[tid + st]; rq[tid] += rq[tid + st]; }
    __syncthreads();
  }
  if (tid == 0) {
    const float mean = rs[0] * (1.f / NB);
    const float var = rq[0] * (1.f / NB) - mean * mean;
    const float sc = bn_g[n] * rsqrtf(var + 1e-5f);
    bnp[2 * n] = sc;
    bnp[2 * n + 1] = bn_b[n] - mean * sc;
  }
}

// =====================================================================
// Kernel D2: BN + sigmoid -> output1; 62->2 FC -> output (unchanged).
// =====================================================================
__global__ __launch_bounds__(64) void k_bn_out(
    const float* __restrict__ zmat, const float* __restrict__ bnp,
    const float* __restrict__ fc4_w, const float* __restrict__ fc4_b,
    float* __restrict__ out) {
  const int b = blockIdx.x;
  const int lane = threadIdx.x;
  float o1 = 0.f;
  if (lane < NC) {
    float z = zmat[b * NC + lane];
    z = z * bnp[2 * lane] + bnp[2 * lane + 1];
    o1 = 1.f / (1.f + __expf(-z));
    out[b * NC + lane] = o1;
  }
  float p0 = (lane < NC) ? o1 * fc4_w[lane] : 0.f;
  float p1 = (lane < NC) ? o1 * fc4_w[NC + lane] : 0.f;
#pragma unroll
  for (int off = 32; off > 0; off >>= 1) {
    p0 += __shfl_down(p0, off, 64);
    p1 += __shfl_down(p1, off, 64);
  }
  if (lane == 0) {
    out[NB * NC + b * 2 + 0] = p0 + fc4_b[0];
    out[NB * NC + b * 2 + 1] = p1 + fc4_b[1];
  }
}

extern "C" void kernel_launch(void* const* d_in, const int* in_sizes, int n_in,
                              void* d_out, int out_size, void* d_ws, size_t ws_size,
                              hipStream_t stream) {
  const float* de      = (const float*)d_in[0];
  const float* pcc     = (const float*)d_in[1];
  const float* Aadj    = (const float*)d_in[2];
  // d_in[3] conv_w, d_in[4] conv_b: dead (gate cancels in trace-normalized SPD)
  const float* hconv_w = (const float*)d_in[5];
  const float* hconv_b = (const float*)d_in[6];
  const float* hlin_w  = (const float*)d_in[7];
  const float* hlin_b  = (const float*)d_in[8];
  const float* econv_w = (const float*)d_in[9];
  const float* econv_b = (const float*)d_in[10];
  const float* elin_w  = (const float*)d_in[11];
  const float* elin_b  = (const float*)d_in[12];
  const float* att_w1  = (const float*)d_in[13];
  const float* att_b1  = (const float*)d_in[14];
  const float* att_w2  = (const float*)d_in[15];
  const float* gc_w    = (const float*)d_in[16];
  const float* gc_b    = (const float*)d_in[17];
  // d_in[18] wpar: wnorm = exp(w)/exp(w) = 1 exactly for 1-element wpar
  const float* fc_w    = (const float*)d_in[19];
  const float* fc_b    = (const float*)d_in[20];
  const float* bn_g    = (const float*)d_in[21];
  const float* bn_b    = (const float*)d_in[22];
  const float* fc4_w   = (const float*)d_in[23];
  const float* fc4_b   = (const float*)d_in[24];

  float* ws        = (float*)d_ws;
  _Float16* comH   = (_Float16*)ws;                      // 5120*4096 halves = 41.9 MB
  float* hidden    = ws + 10485760;                      //  3,936,256 floats
  float* essential = hidden + (size_t)NB * NC * NC;
  float* zmat      = essential + (size_t)NB * NC * NC;   //     63,488
  float* bnp       = zmat + (size_t)NB * NC;             //        128
  unsigned int* lwHg = (unsigned int*)(bnp + 128);       //      4,096 u32 (2 x 64 x 32)
  unsigned int* w1Hg = lwHg + 4096;                      //        320 u32
  float* rsumG     = (float*)(w1Hg + 512);               //        128
  // total ~74 MB of workspace

  k_spd<<<NB * NBAND, 256, 0, stream>>>(pcc, Aadj, hlin_w, elin_w, att_w1,
                                        comH, lwHg, w1Hg, rsumG);
  k_branch<<<NB * 2, 256, 0, stream>>>(comH, lwHg, w1Hg, rsumG,
      hconv_w, hconv_b, hlin_b,
      econv_w, econv_b, elin_b,
      att_b1, att_w2, hidden, essential);
  k_cheb_fc<<<NB, 256, 0, stream>>>(de, hidden, essential, gc_w, gc_b, fc_w, fc_b, zmat);
  k_bnstats<<<NC, 256, 0, stream>>>(zmat, bn_g, bn_b, bnp);
  k_bn_out<<<NB, 64, 0, stream>>>(zmat, bnp, fc4_w, fc4_b, (float*)d_out);
}

// Round 13
// 180.797 us; speedup vs baseline: 1.4290x; 1.0317x over previous
//
#include <hip/hip_runtime.h>
#include <math.h>

#define NB    1024
#define NC    62
#define NBAND 5
#define NOUT  16
#define NHID  10
#define ZSTR  68   // zS row stride in f16
#define XTW   34   // XcT row stride in u32 (64 f16 + pad; 34%32=2 -> light conflicts)

typedef __attribute__((ext_vector_type(2))) float f32x2;
typedef __attribute__((ext_vector_type(4))) float f32x4;
typedef __attribute__((ext_vector_type(2))) _Float16 f16x2;
typedef __attribute__((ext_vector_type(8))) _Float16 f16x8;
typedef __attribute__((ext_vector_type(2))) __fp16 fp16v2;   // cvt_pkrtz result type
#define FMA2(a, b, c) __builtin_elementwise_fma((a), (b), (c))
#define DOT2(a, b, c) __builtin_amdgcn_fdot2((a), (b), (c), false)

__device__ __forceinline__ f16x2 u2h(unsigned int u) { return __builtin_bit_cast(f16x2, u); }
__device__ __forceinline__ unsigned int pk2u(float x, float y) {
  const fp16v2 v = __builtin_amdgcn_cvt_pkrtz(x, y);
  return __builtin_bit_cast(unsigned int, v);
}

// =====================================================================
// Kernel A (v12, MFMA SYRK): gate-cancelled SPD.
//   com[b,k] = 0.5*(N(relu(pcc_t)) + N(relu(A))) + 1e-5*I, f16 output.
// Xc is PRE-SCALED by sqrt(0.5/trace) and stored TRANSPOSED in LDS as
// XcT[c][i] f16 (i-pairs pack into u32 at [c][p] — free transpose from
// the existing per-thread row-pair ownership). Both MFMA operands read
// XcT rows with the k_branch-v11-validated fragment recipe; both
// sources accumulate into one acc (pre-scaled), 16 MFMA/wave total.
// =====================================================================
__global__ __launch_bounds__(256) void k_spd(
    const float* __restrict__ pcc, const float* __restrict__ Aadj,
    const float* __restrict__ hlin_w, const float* __restrict__ elin_w,
    const float* __restrict__ att_w1,
    _Float16* __restrict__ comH, unsigned int* __restrict__ lwHg,
    unsigned int* __restrict__ w1Hg, float* __restrict__ rsumG) {
  const int bk = (blockIdx.x & 7) * 640 + (blockIdx.x >> 3);  // XCD swizzle, 5120%8==0
  const int b = bk / NBAND, k = bk % NBAND;
  __shared__ __align__(16) unsigned int XcT[64 * XTW];   // 8704 B, f16 [c][i]
  __shared__ float red4a[4], red4b[4];
  const int tid = threadIdx.x;
  const int wave = tid >> 6, lane = tid & 63;
  const int p = tid >> 3, q8 = tid & 7, c0 = q8 * 8;
  const bool act = (p < 31);
  const int r0 = 2 * p, r1 = r0 + 1;
  const int mrow = lane & 15, g = lane >> 4;

  float ld0[8], ld1[8];   // src0 rows (then centered values)
  float lA0[8], lA1[8];   // Aadj prefetch / src1 centered values

  // center in regs; sq -> red[wave]. Inactive threads produce zeros.
  auto center = [&](float (&a0)[8], float (&a1)[8], float* red) -> void {
    float s0 = 0.f, s1 = 0.f;
#pragma unroll
    for (int u = 0; u < 8; ++u) { s0 += a0[u]; s1 += a1[u]; }
    s0 += __shfl_xor(s0, 1, 64); s0 += __shfl_xor(s0, 2, 64); s0 += __shfl_xor(s0, 4, 64);
    s1 += __shfl_xor(s1, 1, 64); s1 += __shfl_xor(s1, 2, 64); s1 += __shfl_xor(s1, 4, 64);
    const float m0 = s0 * (1.f / NC), m1 = s1 * (1.f / NC);
    float sq = 0.f;
#pragma unroll
    for (int u = 0; u < 8; ++u) {
      const bool in = act && (c0 + u < NC);
      const float cv0 = in ? (a0[u] - m0) : 0.f;
      const float cv1 = in ? (a1[u] - m1) : 0.f;
      a0[u] = cv0;
      a1[u] = cv1;
      sq += cv0 * cv0 + cv1 * cv1;
    }
#pragma unroll
    for (int off = 1; off < 64; off <<= 1) sq += __shfl_xor(sq, off, 64);
    if (lane == 0) red[wave] = sq;
  };

  // scaled f16 pack + transpose write: XcT[c0+u][p] = {sc*a0[u], sc*a1[u]}
  auto xct_write = [&](const float (&a0)[8], const float (&a1)[8], float sc) -> void {
#pragma unroll
    for (int u = 0; u < 8; ++u)
      XcT[(c0 + u) * XTW + p] = pk2u(sc * a0[u], sc * a1[u]);
  };

  // MFMA fragment from XcT row (k_branch-v11-validated layout):
  // lane holds 8 f16 at k = 32s + 8g .. +7 of the given row.
  auto fragread = [&](int row, int s) -> f16x8 {
    const unsigned int* pp = &XcT[row * XTW + 16 * s + 4 * g];
    const uint2 a = *reinterpret_cast<const uint2*>(pp);
    const uint2 b2 = *reinterpret_cast<const uint2*>(pp + 2);
    const uint4 v = make_uint4(a.x, a.y, b2.x, b2.y);
    return __builtin_bit_cast(f16x8, v);
  };

  // ---- src0 = relu(pcc[b,:,:,k]) : stride-5 scalar loads
#pragma unroll
  for (int u = 0; u < 8; ++u) { ld0[u] = 0.f; ld1[u] = 0.f; }
  if (act) {
    const float* s0p = pcc + ((size_t)(b * NC + r0) * NC + c0) * NBAND + k;
    const float* s1p = pcc + ((size_t)(b * NC + r1) * NC + c0) * NBAND + k;
#pragma unroll
    for (int u = 0; u < 8; ++u) {
      if (c0 + u < NC) {
        ld0[u] = fmaxf(s0p[u * NBAND], 0.f);
        ld1[u] = fmaxf(s1p[u * NBAND], 0.f);
      }
    }
  }
  center(ld0, ld1, red4a);

  // prefetch src1 = Aadj rows (latency hidden under barrier+write+MFMA0)
#pragma unroll
  for (int u = 0; u < 8; ++u) { lA0[u] = 0.f; lA1[u] = 0.f; }
  if (act) {
    const float* a0p = Aadj + ((size_t)(b * NBAND + k) * NC + r0) * NC + c0;
    const float* a1p = Aadj + ((size_t)(b * NBAND + k) * NC + r1) * NC + c0;
#pragma unroll
    for (int e = 0; e < 4; ++e) {
      const int c = c0 + 2 * e;
      if (c + 1 < NC) {
        const float2 v0 = *reinterpret_cast<const float2*>(a0p + 2 * e);
        const float2 v1 = *reinterpret_cast<const float2*>(a1p + 2 * e);
        lA0[2 * e] = v0.x; lA0[2 * e + 1] = v0.y;
        lA1[2 * e] = v1.x; lA1[2 * e + 1] = v1.y;
      } else if (c < NC) {
        lA0[2 * e] = a0p[2 * e];
        lA1[2 * e] = a1p[2 * e];
      }
    }
  }
  __syncthreads();   // (1) red4a ready

  const float tra0 = red4a[0] + red4a[1] + red4a[2] + red4a[3];
  xct_write(ld0, ld1, sqrtf(0.5f / tra0));
  __syncthreads();   // (2) XcT(src0) ready

  // ---- MFMA src0: G rows 16*wave..+15, all 4 col-tiles
  f32x4 acc[4];
#pragma unroll
  for (int n = 0; n < 4; ++n) acc[n] = (f32x4){0.f, 0.f, 0.f, 0.f};
  {
    const f16x8 A0 = fragread(16 * wave + mrow, 0);
    const f16x8 A1 = fragread(16 * wave + mrow, 1);
#pragma unroll
    for (int n = 0; n < 4; ++n) {
      const f16x8 B0 = fragread(16 * n + mrow, 0);
      const f16x8 B1 = fragread(16 * n + mrow, 1);
      acc[n] = __builtin_amdgcn_mfma_f32_16x16x32_f16(A0, B0, acc[n], 0, 0, 0);
      acc[n] = __builtin_amdgcn_mfma_f32_16x16x32_f16(A1, B1, acc[n], 0, 0, 0);
    }
  }

  // ---- src1: relu + center (overlaps MFMA on the VALU pipe)
#pragma unroll
  for (int u = 0; u < 8; ++u) { lA0[u] = fmaxf(lA0[u], 0.f); lA1[u] = fmaxf(lA1[u], 0.f); }
  center(lA0, lA1, red4b);
  __syncthreads();   // (3) MFMA src0 reads done; red4b ready

  const float tra1 = red4b[0] + red4b[1] + red4b[2] + red4b[3];
  xct_write(lA0, lA1, sqrtf(0.5f / tra1));
  __syncthreads();   // (4) XcT(src1) ready

  {
    const f16x8 A0 = fragread(16 * wave + mrow, 0);
    const f16x8 A1 = fragread(16 * wave + mrow, 1);
#pragma unroll
    for (int n = 0; n < 4; ++n) {
      const f16x8 B0 = fragread(16 * n + mrow, 0);
      const f16x8 B1 = fragread(16 * n + mrow, 1);
      acc[n] = __builtin_amdgcn_mfma_f32_16x16x32_f16(A0, B0, acc[n], 0, 0, 0);
      acc[n] = __builtin_amdgcn_mfma_f32_16x16x32_f16(A1, B1, acc[n], 0, 0, 0);
    }
  }

  // ---- epilogue: diag + f16 store. r = 16*wave+4g+reg, col = 16n+mrow.
  // Pad rows/cols are exact zeros (XcT rows 62,63 zero) -> safe for k_branch.
#pragma unroll
  for (int reg = 0; reg < 4; ++reg) {
    const int r = 16 * wave + 4 * g + reg;
#pragma unroll
    for (int n = 0; n < 4; ++n) {
      float v = acc[n][reg];
      if (n == wave && mrow == 4 * g + reg) v += 1e-5f;   // diagonal
      comH[(size_t)bk * 4096 + r * 64 + 16 * n + mrow] = (_Float16)v;
    }
  }

  // ---- block 0 epilogue: lwHg row-major f16 [br][o][c], w1H, row sums
  if (blockIdx.x == 0) {
    for (int t = tid; t < 2 * 64 * 32; t += 256) {
      const int brx = t >> 11, rem = t & 2047, o = rem >> 5, cp = rem & 31;
      const float* lwsrc = brx ? elin_w : hlin_w;
      float lo = 0.f, hi = 0.f;
      if (o < NC) {
        const int c = 2 * cp;
        if (c < NC)     lo = lwsrc[o * NC + c];
        if (c + 1 < NC) hi = lwsrc[o * NC + c + 1];
      }
      lwHg[t] = pk2u(lo, hi);   // [br][o][c-pair] row-major
    }
    for (int t = tid; t < NHID * 32; t += 256) {
      const int h = t >> 5, op = t & 31;
      const float lo = (2 * op < NC) ? att_w1[h * NC + 2 * op] : 0.f;
      const float hi = (2 * op + 1 < NC) ? att_w1[h * NC + 2 * op + 1] : 0.f;
      w1Hg[t] = pk2u(lo, hi);
    }
    if (tid < 64) {
      float sh = 0.f, se = 0.f;
      if (tid < NC) {
        for (int c = 0; c < NC; ++c) { sh += hlin_w[tid * NC + c]; se += elin_w[tid * NC + c]; }
      }
      rsumG[tid] = sh;
      rsumG[64 + tid] = se;
    }
  }
}

// =====================================================================
// Kernel B (v11, MFMA): unchanged from round 12 (validated).
// =====================================================================
__global__ __launch_bounds__(256, 2) void k_branch(
    const _Float16* __restrict__ comH, const unsigned int* __restrict__ lwHg,
    const unsigned int* __restrict__ w1Hg, const float* __restrict__ rsumG,
    const float* __restrict__ hconv_w, const float* __restrict__ hconv_b,
    const float* __restrict__ hlin_b,
    const float* __restrict__ econv_w, const float* __restrict__ econv_b,
    const float* __restrict__ elin_b,
    const float* __restrict__ att_b1,  const float* __restrict__ att_w2,
    float* __restrict__ hiddenO, float* __restrict__ essentialO) {
  const int bid = (blockIdx.x & 7) * 256 + (blockIdx.x >> 3);  // XCD swizzle
  const int b = bid >> 1, br = bid & 1;

  const float* __restrict__ cw = br ? econv_w : hconv_w;
  const float* __restrict__ cb = br ? econv_b : hconv_b;
  const float* __restrict__ lb = br ? elin_b : hlin_b;
  float* __restrict__ outp = br ? essentialO : hiddenO;

  __shared__ __align__(16) unsigned int comS[64 * 32];     // 8 KB, XOR-swizzled
  __shared__ __align__(16) _Float16 zS[4][16 * ZSTR];      // 8.7 KB, per-wave
  __shared__ __align__(16) unsigned int w1S[NHID * 32];    // o-pair f16
  __shared__ float scoreS[4][16];
  __shared__ float b1S[16], w2S[16], cwS[8], cbS[8];

  const int tid = threadIdx.x;
  const int w = tid >> 6, lane = tid & 63;
  const int mrow = lane & 15;       // A-row within strip / C col-within-tile
  const int g = lane >> 4;          // k-group / C row-group

  // ---- param fills (block-wide -> one barrier)
  for (int t = tid; t < NHID * 32; t += 256) w1S[t] = w1Hg[t];
  if (tid < NHID) { b1S[tid] = att_b1[tid]; w2S[tid] = att_w2[tid]; }
  if (tid < NBAND) { cwS[tid] = cw[tid]; cbS[tid] = cb[tid]; }

  // ---- B-frags in registers (band-invariant): B[s][n], col = 16n+mrow
  f16x8 Bf[2][4];
  float rsumR[4], lbR[4];
#pragma unroll
  for (int n = 0; n < 4; ++n) {
    const int col = 16 * n + mrow;
    rsumR[n] = rsumG[br * 64 + col];
    lbR[n] = (col < NC) ? lb[col] : 0.f;
#pragma unroll
    for (int s = 0; s < 2; ++s) {
      const uint4 v = *reinterpret_cast<const uint4*>(lwHg + br * 2048 + col * 32 + s * 16 + g * 4);
      Bf[s][n] = __builtin_bit_cast(f16x8, v);
    }
  }
  __syncthreads();   // w1S/b1S/w2S/cwS/cbS visible to all waves

  // ---- staging: wave w stages ITS strip rows 16w..16w+15 (128 uint4).
  const uint4* gsrc = reinterpret_cast<const uint4*>(comH + (size_t)(b * NBAND) * 4096);
  uint4 pf[2];
  auto stage_issue = [&](int band) {
#pragma unroll
    for (int i = 0; i < 2; ++i) pf[i] = gsrc[band * 512 + w * 128 + i * 64 + lane];
  };
  auto stage_write = [&]() {
#pragma unroll
    for (int i = 0; i < 2; ++i) {
      const int idx = i * 64 + lane;          // within strip: 0..127
      const int row = 16 * w + (idx >> 3), slot = idx & 7;
      const int sb = (slot * 16) ^ ((row & 7) << 4);   // swizzled byte in row
      *reinterpret_cast<uint4*>(comS + row * 32 + sb / 4) = pf[i];
    }
  };

  auto a_frag = [&](int s) -> f16x8 {
    const int row = 16 * w + mrow;
    const int sb = (64 * s + 16 * g) ^ ((row & 7) << 4);
    return __builtin_bit_cast(f16x8, *reinterpret_cast<const uint4*>(comS + row * 32 + sb / 4));
  };

  stage_issue(0);
  stage_write();

  f32x4 oacc[4];
#pragma unroll
  for (int n = 0; n < 4; ++n) oacc[n] = (f32x4){0.f, 0.f, 0.f, 0.f};
  float denom[4] = {0.f, 0.f, 0.f, 0.f};
  float mrun[4] = {-1e30f, -1e30f, -1e30f, -1e30f};

  _Float16* zSw = &zS[w][0];   // wave-private
  const int rowz = lane >> 2, qz = lane & 3;   // scorer mapping

#pragma unroll 1
  for (int kb = 0; kb < NBAND; ++kb) {
    if (kb < NBAND - 1) stage_issue(kb + 1);   // T14: issue early

    // ---- MFMA GEMM: acc[n] = A(strip) x B[n], K=64 in 2 steps
    const f16x8 A0 = a_frag(0);
    const f16x8 A1 = a_frag(1);
    f32x4 acc[4];
#pragma unroll
    for (int n = 0; n < 4; ++n) {
      acc[n] = __builtin_amdgcn_mfma_f32_16x16x32_f16(A0, Bf[0][n], (f32x4){0.f, 0.f, 0.f, 0.f}, 0, 0, 0);
      acc[n] = __builtin_amdgcn_mfma_f32_16x16x32_f16(A1, Bf[1][n], acc[n], 0, 0, 0);
    }

    if (kb < NBAND - 1) stage_write();   // in-order DS: lands after A reads

    // ---- sigmoid in C-layout regs; write z to wave-private zS (f16)
    const float ck = cwS[kb], dk = cbS[kb];
#pragma unroll
    for (int n = 0; n < 4; ++n) {
      const float base = dk * rsumR[n] + lbR[n];
#pragma unroll
      for (int reg = 0; reg < 4; ++reg) {
        const float zv = 1.f / (1.f + __expf(-(ck * acc[n][reg] + base)));
        acc[n][reg] = zv;
        zSw[(4 * g + reg) * ZSTR + 16 * n + mrow] = (_Float16)zv;
      }
    }

    // ---- scorer over zS rows: row = lane>>2, q = lane&3
    {
      const _Float16* zr = zSw + rowz * ZSTR + qz * 16;
      unsigned int zh[8];
#pragma unroll
      for (int j = 0; j < 4; ++j) {
        const uint2 v = *reinterpret_cast<const uint2*>(zr + 4 * j);  // 8B-aligned
        zh[2 * j] = v.x;
        zh[2 * j + 1] = v.y;
      }
      float sacc = 0.f;
#pragma unroll
      for (int t = 0; t < 5; ++t) {
        const int hA = 2 * t, hB = 2 * t + 1;
        const uint4 wa0 = *reinterpret_cast<const uint4*>(w1S + hA * 32 + qz * 8);
        const uint4 wa1 = *reinterpret_cast<const uint4*>(w1S + hA * 32 + qz * 8 + 4);
        const uint4 wb0 = *reinterpret_cast<const uint4*>(w1S + hB * 32 + qz * 8);
        const uint4 wb1 = *reinterpret_cast<const uint4*>(w1S + hB * 32 + qz * 8 + 4);
        const unsigned int wau[8] = {wa0.x, wa0.y, wa0.z, wa0.w, wa1.x, wa1.y, wa1.z, wa1.w};
        const unsigned int wbu[8] = {wb0.x, wb0.y, wb0.z, wb0.w, wb1.x, wb1.y, wb1.z, wb1.w};
        float pA = 0.f, pB = 0.f;
#pragma unroll
        for (int u = 0; u < 8; ++u) {
          pA = DOT2(u2h(zh[u]), u2h(wau[u]), pA);
          pB = DOT2(u2h(zh[u]), u2h(wbu[u]), pB);
        }
        pA += __shfl_xor(pA, 1, 64); pA += __shfl_xor(pA, 2, 64);
        pB += __shfl_xor(pB, 1, 64); pB += __shfl_xor(pB, 2, 64);
        const float exA = __expf(2.f * (pA + b1S[hA]));
        const float exB = __expf(2.f * (pB + b1S[hB]));
        sacc += w2S[hA] * (1.f - 2.f / (exA + 1.f));
        sacc += w2S[hB] * (1.f - 2.f / (exB + 1.f));
      }
      if (qz == 0) scoreS[w][rowz] = sacc;
    }

    // ---- online softmax on C-layout accs (rows 4g+reg)
#pragma unroll
    for (int reg = 0; reg < 4; ++reg) {
      const float sc = scoreS[w][4 * g + reg];     // in-order after write
      const float nm = fmaxf(mrun[reg], sc);
      const float f = __expf(mrun[reg] - nm), e = __expf(sc - nm);
      denom[reg] = denom[reg] * f + e;
#pragma unroll
      for (int n = 0; n < 4; ++n)
        oacc[n][reg] = oacc[n][reg] * f + e * acc[n][reg];
      mrun[reg] = nm;
    }
  }

  // ---- store: r = 16w + 4g + reg, col = 16n + mrow
#pragma unroll
  for (int reg = 0; reg < 4; ++reg) {
    const int r = 16 * w + 4 * g + reg;
    if (r < NC) {
      const float inv = 1.f / denom[reg];
#pragma unroll
      for (int n = 0; n < 4; ++n) {
        const int col = 16 * n + mrow;
        if (col < NC) outp[(size_t)b * (NC * NC) + r * NC + col] = oacc[n][reg] * inv;
      }
    }
  }
}

// =====================================================================
// Kernel C: Chebyshev GCN + feature + 992->62 FC (unchanged).
// =====================================================================
__global__ __launch_bounds__(256) void k_cheb_fc(
    const float* __restrict__ de, const float* __restrict__ hidden,
    const float* __restrict__ essential, const float* __restrict__ gc_w,
    const float* __restrict__ gc_b, const float* __restrict__ fc_w,
    const float* __restrict__ fc_b, float* __restrict__ zmat) {
  const int b = blockIdx.x;
  __shared__ float hidS[NC * NC], essS[NC * NC];
  __shared__ float t0S[NC * NOUT], t1S[NC * NOUT];
  __shared__ float featS[NC * NOUT];
  __shared__ float deS[NC * NBAND];
  __shared__ float red2[256];
  const int tid = threadIdx.x;

  for (int t = tid; t < NC * NBAND; t += 256) deS[t] = de[b * NC * NBAND + t];
  for (int t = tid; t < NC * NC; t += 256) {
    hidS[t] = hidden[b * NC * NC + t];
    essS[t] = essential[b * NC * NC + t];
  }
  __syncthreads();
  for (int t = tid; t < NC * NOUT; t += 256) {
    const int i = t / NOUT, f = t % NOUT;
    float a0 = gc_b[f];
    float a1 = 0.f;
#pragma unroll
    for (int qq = 0; qq < NBAND; ++qq) {
      const float d = deS[i * NBAND + qq];
      a0 += d * gc_w[qq * NOUT + f];
      a1 += d * gc_w[(NBAND + qq) * NOUT + f];
    }
    t0S[t] = a0;
    t1S[t] = a1;
  }
  __syncthreads();
  for (int t = tid; t < NC * NOUT; t += 256) {
    const int i = t / NOUT, f = t % NOUT;
    float sh = 0.f, se = 0.f;
    for (int jj = 0; jj < NC; ++jj) {
      const float t1 = t1S[jj * NOUT + f];
      sh += hidS[i * NC + jj] * t1;
      se += essS[i * NC + jj] * t1;
    }
    const float gb1 = gc_b[NOUT + f];
    const float h = fmaxf(t0S[t] + sh + gb1, 0.f);
    const float e = fmaxf(t0S[t] + se + gb1, 0.f);
    featS[t] = 0.5f * (h + e);
  }
  __syncthreads();
  {
    const int n = tid >> 2, qq = tid & 3;
    float p = 0.f;
    if (n < NC) {
      const float* fw = fc_w + n * (NC * NOUT) + qq * 248;
      const float* fs = featS + qq * 248;
      for (int m = 0; m < 248; ++m) p += fs[m] * fw[m];
    }
    red2[tid] = p;
    __syncthreads();
    if (tid < NC) {
      const float z = red2[tid * 4] + red2[tid * 4 + 1] + red2[tid * 4 + 2] + red2[tid * 4 + 3] + fc_b[tid];
      zmat[b * NC + tid] = z;
    }
  }
}

// =====================================================================
// Kernel D1: batch-norm statistics (unchanged).
// =====================================================================
__global__ __launch_bounds__(256) void k_bnstats(
    const float* __restrict__ zmat, const float* __restrict__ bn_g,
    const float* __restrict__ bn_b, float* __restrict__ bnp) {
  const int n = blockIdx.x;
  __shared__ float rs[256], rq[256];
  const int tid = threadIdx.x;
  float s = 0.f, sq = 0.f;
  for (int r = tid; r < NB; r += 256) {
    const float v = zmat[r * NC + n];
    s += v;
    sq += v * v;
  }
  rs[tid] = s; rq[tid] = sq;
  __syncthreads();
  for (int st = 128; st > 0; st >>= 1) {
    if (tid < st) { rs[tid] += rs[tid + st]; rq[tid] += rq[tid + st]; }
    __syncthreads();
  }
  if (tid == 0) {
    const float mean = rs[0] * (1.f / NB);
    const float var = rq[0] * (1.f / NB) - mean * mean;
    const float sc = bn_g[n] * rsqrtf(var + 1e-5f);
    bnp[2 * n] = sc;
    bnp[2 * n + 1] = bn_b[n] - mean * sc;
  }
}

// =====================================================================
// Kernel D2: BN + sigmoid -> output1; 62->2 FC -> output (unchanged).
// =====================================================================
__global__ __launch_bounds__(64) void k_bn_out(
    const float* __restrict__ zmat, const float* __restrict__ bnp,
    const float* __restrict__ fc4_w, const float* __restrict__ fc4_b,
    float* __restrict__ out) {
  const int b = blockIdx.x;
  const int lane = threadIdx.x;
  float o1 = 0.f;
  if (lane < NC) {
    float z = zmat[b * NC + lane];
    z = z * bnp[2 * lane] + bnp[2 * lane + 1];
    o1 = 1.f / (1.f + __expf(-z));
    out[b * NC + lane] = o1;
  }
  float p0 = (lane < NC) ? o1 * fc4_w[lane] : 0.f;
  float p1 = (lane < NC) ? o1 * fc4_w[NC + lane] : 0.f;
#pragma unroll
  for (int off = 32; off > 0; off >>= 1) {
    p0 += __shfl_down(p0, off, 64);
    p1 += __shfl_down(p1, off, 64);
  }
  if (lane == 0) {
    out[NB * NC + b * 2 + 0] = p0 + fc4_b[0];
    out[NB * NC + b * 2 + 1] = p1 + fc4_b[1];
  }
}

extern "C" void kernel_launch(void* const* d_in, const int* in_sizes, int n_in,
                              void* d_out, int out_size, void* d_ws, size_t ws_size,
                              hipStream_t stream) {
  const float* de      = (const float*)d_in[0];
  const float* pcc     = (const float*)d_in[1];
  const float* Aadj    = (const float*)d_in[2];
  // d_in[3] conv_w, d_in[4] conv_b: dead (gate cancels in trace-normalized SPD)
  const float* hconv_w = (const float*)d_in[5];
  const float* hconv_b = (const float*)d_in[6];
  const float* hlin_w  = (const float*)d_in[7];
  const float* hlin_b  = (const float*)d_in[8];
  const float* econv_w = (const float*)d_in[9];
  const float* econv_b = (const float*)d_in[10];
  const float* elin_w  = (const float*)d_in[11];
  const float* elin_b  = (const float*)d_in[12];
  const float* att_w1  = (const float*)d_in[13];
  const float* att_b1  = (const float*)d_in[14];
  const float* att_w2  = (const float*)d_in[15];
  const float* gc_w    = (const float*)d_in[16];
  const float* gc_b    = (const float*)d_in[17];
  // d_in[18] wpar: wnorm = exp(w)/exp(w) = 1 exactly for 1-element wpar
  const float* fc_w    = (const float*)d_in[19];
  const float* fc_b    = (const float*)d_in[20];
  const float* bn_g    = (const float*)d_in[21];
  const float* bn_b    = (const float*)d_in[22];
  const float* fc4_w   = (const float*)d_in[23];
  const float* fc4_b   = (const float*)d_in[24];

  float* ws        = (float*)d_ws;
  _Float16* comH   = (_Float16*)ws;                      // 5120*4096 halves = 41.9 MB
  float* hidden    = ws + 10485760;                      //  3,936,256 floats
  float* essential = hidden + (size_t)NB * NC * NC;
  float* zmat      = essential + (size_t)NB * NC * NC;   //     63,488
  float* bnp       = zmat + (size_t)NB * NC;             //        128
  unsigned int* lwHg = (unsigned int*)(bnp + 128);       //      4,096 u32 (2 x 64 x 32)
  unsigned int* w1Hg = lwHg + 4096;                      //        320 u32
  float* rsumG     = (float*)(w1Hg + 512);               //        128
  // total ~74 MB of workspace

  k_spd<<<NB * NBAND, 256, 0, stream>>>(pcc, Aadj, hlin_w, elin_w, att_w1,
                                        comH, lwHg, w1Hg, rsumG);
  k_branch<<<NB * 2, 256, 0, stream>>>(comH, lwHg, w1Hg, rsumG,
      hconv_w, hconv_b, hlin_b,
      econv_w, econv_b, elin_b,
      att_b1, att_w2, hidden, essential);
  k_cheb_fc<<<NB, 256, 0, stream>>>(de, hidden, essential, gc_w, gc_b, fc_w, fc_b, zmat);
  k_bnstats<<<NC, 256, 0, stream>>>(zmat, bn_g, bn_b, bnp);
  k_bn_out<<<NB, 64, 0, stream>>>(zmat, bnp, fc4_w, fc4_b, (float*)d_out);
}